// Round 1
// baseline (572.682 us; speedup 1.0000x reference)
//
#include <hip/hip_runtime.h>
#include <stdint.h>

#define BB 16
#define NN 102000
#define NCLS 35
#define RSTRIDE 40
#define PRE 1024
#define CAP 2048
#define MAXDET 300
#define NBUCK 4096
#define CONF_T 0.25f
#define IOU_T 0.45f
#define BUCK_BASE 0x3E800000u

// ---- workspace layout (bytes) ----
#define SCORES_OFF ((size_t)0)
#define SCORES_BYTES ((size_t)BB * NN * 4)                 // 6,528,000
#define CNT_OFF (SCORES_OFF + SCORES_BYTES)                // 64 B (16 u32 + pad)
#define CANDS_OFF (CNT_OFF + 64)
#define CANDS_BYTES ((size_t)BB * CAP * 8)
#define BOXES_OFF (CANDS_OFF + CANDS_BYTES)
#define BOXES_BYTES ((size_t)BB * PRE * 16)
#define SVAL_OFF (BOXES_OFF + BOXES_BYTES)
#define SVAL_BYTES ((size_t)BB * PRE * 4)
#define CLS_OFF (SVAL_OFF + SVAL_BYTES)
#define CLS_BYTES ((size_t)BB * PRE * 4)
#define MASK_OFF (CLS_OFF + CLS_BYTES)
#define MASK_BYTES ((size_t)BB * PRE * 16 * 8)             // 2 MB

// ============================================================
// Kernel 1: score every box. score = (obj>0.25 && conf>0.25) ? conf : 0
// conf = max_j(cls_j * obj)  (per-class product then max, like the reference)
// ============================================================
__global__ __launch_bounds__(256) void k_score(const float* __restrict__ pred,
                                               float* __restrict__ scores) {
    int b = blockIdx.y;
    int i = blockIdx.x * 256 + threadIdx.x;
    if (i >= NN) return;
    const float4* row = (const float4*)(pred + ((size_t)b * NN + i) * RSTRIDE);
    float4 r1 = row[1];            // floats 4..7: obj, cls0, cls1, cls2
    float obj = r1.x;
    float score = 0.0f;
    if (obj > CONF_T) {
        float best = r1.y * obj;
        best = fmaxf(best, r1.z * obj);
        best = fmaxf(best, r1.w * obj);
#pragma unroll
        for (int k = 2; k <= 9; ++k) {   // floats 8..39: cls3..cls34
            float4 r = row[k];
            best = fmaxf(best, r.x * obj);
            best = fmaxf(best, r.y * obj);
            best = fmaxf(best, r.z * obj);
            best = fmaxf(best, r.w * obj);
        }
        if (best > CONF_T) score = best;
    }
    scores[(size_t)b * NN + i] = score;
}

// ============================================================
// Kernel 2: per-batch histogram of score bits + cut-bucket find + gather keys
// key = (score_bits << 32) | ~idx  -> u64 descending order == (value desc, idx asc)
// ============================================================
__global__ __launch_bounds__(1024) void k_select(const float* __restrict__ scores,
                                                 unsigned int* __restrict__ cnt,
                                                 unsigned long long* __restrict__ cands) {
    __shared__ unsigned int hist[NBUCK];
    __shared__ int sA[1024], sB[1024];
    __shared__ int cutB;
    int b = blockIdx.x, tid = threadIdx.x;
    for (int k = tid; k < NBUCK; k += 1024) hist[k] = 0u;
    if (tid == 0) cutB = 0;
    __syncthreads();
    const float* sb = scores + (size_t)b * NN;
    for (int i = tid; i < NN; i += 1024) {
        float s = sb[i];
        if (s > 0.0f) {
            unsigned int bits = __float_as_uint(s);
            unsigned int bk = (bits - BUCK_BASE) >> 12;
            if (bk > NBUCK - 1u) bk = NBUCK - 1u;
            atomicAdd(&hist[bk], 1u);
        }
    }
    __syncthreads();
    // inclusive suffix sums over 1024 thread-chunks (4 buckets each)
    int h0 = hist[4 * tid + 0], h1 = hist[4 * tid + 1];
    int h2 = hist[4 * tid + 2], h3 = hist[4 * tid + 3];
    sA[tid] = h0 + h1 + h2 + h3;
    __syncthreads();
    int* src = sA;
    int* dst = sB;
    for (int off = 1; off < 1024; off <<= 1) {
        int x = src[tid];
        if (tid + off < 1024) x += src[tid + off];
        dst[tid] = x;
        __syncthreads();
        int* t_ = src; src = dst; dst = t_;
    }
    int nxt = (tid + 1 < 1024) ? src[tid + 1] : 0;
    int s3 = h3 + nxt;
    int s2 = h2 + s3;
    int s1 = h1 + s2;
    int s0 = h0 + s1;
    // cut = largest bucket c with suffix(c) >= PRE  (unique boundary)
    if (s0 >= PRE && s1 < PRE) cutB = 4 * tid + 0;
    if (s1 >= PRE && s2 < PRE) cutB = 4 * tid + 1;
    if (s2 >= PRE && s3 < PRE) cutB = 4 * tid + 2;
    if (s3 >= PRE && nxt < PRE) cutB = 4 * tid + 3;
    __syncthreads();
    int cut = cutB;
    for (int i = tid; i < NN; i += 1024) {
        float s = sb[i];
        if (s > 0.0f) {
            unsigned int bits = __float_as_uint(s);
            unsigned int bk = (bits - BUCK_BASE) >> 12;
            if (bk > NBUCK - 1u) bk = NBUCK - 1u;
            if ((int)bk >= cut) {
                unsigned int pos = atomicAdd(&cnt[b], 1u);
                if (pos < CAP)
                    cands[(size_t)b * CAP + pos] =
                        ((unsigned long long)bits << 32) | (unsigned int)(~(unsigned int)i);
            }
        }
    }
}

// ============================================================
// Kernel 3: per-batch bitonic sort of candidate keys (desc), top-1024 gather:
// boxes (xyxy), score, cls_id (first-occurrence argmax of cls_j*obj)
// ============================================================
__global__ __launch_bounds__(1024) void k_sort(const unsigned int* __restrict__ cnt,
                                               const unsigned long long* __restrict__ cands,
                                               const float* __restrict__ pred,
                                               float4* __restrict__ boxesWS,
                                               float* __restrict__ svalWS,
                                               float* __restrict__ clsWS) {
    __shared__ unsigned long long keys[CAP];
    int b = blockIdx.x, tid = threadIdx.x;
    int M = (int)cnt[b];
    if (M > CAP) M = CAP;
    for (int k = tid; k < CAP; k += 1024)
        keys[k] = (k < M) ? cands[(size_t)b * CAP + k] : 0ull;
    __syncthreads();
    for (int k = 2; k <= CAP; k <<= 1) {
        for (int j = k >> 1; j > 0; j >>= 1) {
            int p = ((tid & ~(j - 1)) << 1) | (tid & (j - 1));
            int q = p | j;
            unsigned long long a = keys[p], c = keys[q];
            bool desc = (p & k) == 0;
            bool sw = desc ? (a < c) : (a > c);
            if (sw) { keys[p] = c; keys[q] = a; }
            __syncthreads();
        }
    }
    unsigned long long key = keys[tid];
    unsigned int bits = (unsigned int)(key >> 32);
    unsigned int idx = ~(unsigned int)key;
    float sc = __uint_as_float(bits);
    if (bits == 0u || idx >= NN) { idx = 0; sc = 0.0f; }   // pathological pad guard
    const float4* row = (const float4*)(pred + ((size_t)b * NN + idx) * RSTRIDE);
    float4 r0 = row[0];
    float4 r1 = row[1];
    float obj = r1.x;
    float best = r1.y * obj; int bj = 0;
    float p1 = r1.z * obj; if (p1 > best) { best = p1; bj = 1; }
    float p2 = r1.w * obj; if (p2 > best) { best = p2; bj = 2; }
#pragma unroll
    for (int kk = 2; kk <= 9; ++kk) {
        float4 r = row[kk];
        int base = (kk - 2) * 4 + 3;
        float q0 = r.x * obj; if (q0 > best) { best = q0; bj = base + 0; }
        float q1 = r.y * obj; if (q1 > best) { best = q1; bj = base + 1; }
        float q2 = r.z * obj; if (q2 > best) { best = q2; bj = base + 2; }
        float q3 = r.w * obj; if (q3 > best) { best = q3; bj = base + 3; }
    }
    float hx = r0.z * 0.5f;   // exact (power-of-two scale)
    float hy = r0.w * 0.5f;
    boxesWS[b * PRE + tid] = make_float4(r0.x - hx, r0.y - hy, r0.x + hx, r0.y + hy);
    svalWS[b * PRE + tid] = sc;
    clsWS[b * PRE + tid] = (float)bj;
}

// ============================================================
// Kernel 4: column-major suppression mask.
// maskC[b][j][c] bit l  <=>  i=64c+l < j  &&  valid[i]  &&  IoU(i,j) > 0.45
// One wave per column j; ballot builds each 64-bit word.
// ============================================================
__global__ __launch_bounds__(256) void k_mask(const float4* __restrict__ boxesWS,
                                              const float* __restrict__ svalWS,
                                              unsigned long long* __restrict__ maskC) {
    __shared__ float bx1[PRE], by1[PRE], bx2[PRE], by2[PRE], bar[PRE], bsv[PRE];
    int b = blockIdx.y, tid = threadIdx.x;
    for (int i = tid; i < PRE; i += 256) {
        float4 bx = boxesWS[b * PRE + i];
        bx1[i] = bx.x; by1[i] = bx.y; bx2[i] = bx.z; by2[i] = bx.w;
        float aw = fmaxf(bx.z - bx.x, 0.0f);
        float ah = fmaxf(bx.w - bx.y, 0.0f);
        bar[i] = aw * ah;
        bsv[i] = svalWS[b * PRE + i];
    }
    __syncthreads();
    int j = blockIdx.x * 4 + (tid >> 6);
    int lane = tid & 63;
    float jx1 = bx1[j], jy1 = by1[j], jx2 = bx2[j], jy2 = by2[j], ja = bar[j];
    unsigned long long* out = maskC + ((size_t)b * PRE + j) * 16;
    for (int c = 0; c < 16; ++c) {
        unsigned long long word = 0ull;
        if (c * 64 < j) {                      // wave-uniform branch
            int i = c * 64 + lane;
            bool bit = false;
            if (i < j && bsv[i] > 0.0f) {
                float ltx = fmaxf(bx1[i], jx1), lty = fmaxf(by1[i], jy1);
                float rbx = fminf(bx2[i], jx2), rby = fminf(by2[i], jy2);
                float wx = fmaxf(rbx - ltx, 0.0f);
                float wy = fmaxf(rby - lty, 0.0f);
                float inter = wx * wy;                       // two uses -> no contraction
                float denom = ((bar[i] + ja) - inter) + 1e-7f;
                bit = (inter / denom) > IOU_T;               // IEEE divide, like reference
            }
            word = __ballot(bit);
        }
        if (lane == 0) out[c] = word;
    }
}

// ============================================================
// Kernel 5: fixpoint NMS (antitone iteration to the unique greedy fixpoint),
// then exact top-300 ordering of where(keep, s, 0) and output write.
// ============================================================
__global__ __launch_bounds__(1024) void k_nms_out(const float4* __restrict__ boxesWS,
                                                  const float* __restrict__ svalWS,
                                                  const float* __restrict__ clsWS,
                                                  const unsigned long long* __restrict__ maskC,
                                                  float* __restrict__ out) {
    __shared__ unsigned long long supp[16], nsupp[16];
    __shared__ int changed;
    __shared__ int wtot[16], woff[17];
    int b = blockIdx.x, tid = threadIdx.x;
    int lane = tid & 63, w = tid >> 6;
    unsigned long long cm[16];
    const unsigned long long* mrow = maskC + ((size_t)b * PRE + tid) * 16;
#pragma unroll
    for (int k = 0; k < 16; ++k) cm[k] = mrow[k];
    float sv = svalWS[b * PRE + tid];
    if (tid < 16) supp[tid] = 0ull;
    __syncthreads();
    for (int it = 0; it < PRE + 2; ++it) {
        bool nb = false;
#pragma unroll
        for (int k = 0; k < 16; ++k) nb |= ((cm[k] & ~supp[k]) != 0ull);
        unsigned long long word = __ballot(nb);
        __syncthreads();
        if (lane == 0) nsupp[w] = word;
        if (tid == 0) changed = 0;
        __syncthreads();
        if (tid < 16) {
            if (nsupp[tid] != supp[tid]) changed = 1;
            supp[tid] = nsupp[tid];
        }
        __syncthreads();
        if (!changed) break;
    }
    bool keep = (sv > 0.0f) && !((supp[w] >> lane) & 1ull);
    // block-wide exclusive prefix of keep
    unsigned long long km = __ballot(keep);
    int lp = __popcll(km & ((lane == 0) ? 0ull : ((1ull << lane) - 1ull)));
    if (lane == 0) wtot[w] = __popcll(km);
    __syncthreads();
    if (tid == 0) {
        int acc = 0;
        for (int k = 0; k < 16; ++k) { woff[k] = acc; acc += wtot[k]; }
        woff[16] = acc;
    }
    __syncthreads();
    int K = woff[16];
    int keptExcl = woff[w] + lp;
    int slot = keep ? keptExcl : (K + (tid - keptExcl));
    if (slot < MAXDET) {
        float4 bx = boxesWS[b * PRE + tid];
        float cv = clsWS[b * PRE + tid];
        float* o = out + ((size_t)b * MAXDET + slot) * 6;
        o[0] = bx.x; o[1] = bx.y; o[2] = bx.z; o[3] = bx.w;
        o[4] = keep ? sv : 0.0f;
        o[5] = cv;
    }
}

extern "C" void kernel_launch(void* const* d_in, const int* in_sizes, int n_in,
                              void* d_out, int out_size, void* d_ws, size_t ws_size,
                              hipStream_t stream) {
    const float* pred = (const float*)d_in[0];
    float* out = (float*)d_out;
    char* ws = (char*)d_ws;
    float* scores = (float*)(ws + SCORES_OFF);
    unsigned int* cnt = (unsigned int*)(ws + CNT_OFF);
    unsigned long long* cands = (unsigned long long*)(ws + CANDS_OFF);
    float4* boxesWS = (float4*)(ws + BOXES_OFF);
    float* svalWS = (float*)(ws + SVAL_OFF);
    float* clsWS = (float*)(ws + CLS_OFF);
    unsigned long long* maskC = (unsigned long long*)(ws + MASK_OFF);

    hipMemsetAsync(cnt, 0, 64, stream);
    k_score<<<dim3((NN + 255) / 256, BB), 256, 0, stream>>>(pred, scores);
    k_select<<<BB, 1024, 0, stream>>>(scores, cnt, cands);
    k_sort<<<BB, 1024, 0, stream>>>(cnt, cands, pred, boxesWS, svalWS, clsWS);
    k_mask<<<dim3(PRE / 4, BB), 256, 0, stream>>>(boxesWS, svalWS, maskC);
    k_nms_out<<<BB, 1024, 0, stream>>>(boxesWS, svalWS, clsWS, maskC, out);
}